// Round 9
// baseline (289.210 us; speedup 1.0000x reference)
//
#include <hip/hip_runtime.h>
#include <hip/hip_bf16.h>

#define NN 10000
#define EE 160000
#define DD 512
#define GG 64
#define OUTC 128
#define NBLK2 1256          // gemm grid: 157 row-panels x 8 col-panels

typedef __attribute__((ext_vector_type(8))) short bf16x8;
typedef __attribute__((ext_vector_type(4))) float f32x4;

static __device__ __forceinline__ unsigned short f2bf(float f) {
  unsigned u = __builtin_bit_cast(unsigned, f);
  unsigned rounding = 0x7fffu + ((u >> 16) & 1u);
  u += rounding;
  return (unsigned short)(u >> 16);
}

static __device__ __forceinline__ void gload_lds16(const void* g, void* l) {
  __builtin_amdgcn_global_load_lds(
      (const __attribute__((address_space(1))) unsigned*)g,
      (__attribute__((address_space(3))) unsigned*)l, 16, 0, 0);
}

struct WPtrs { const float* p[10]; };

// ---------------- prep: hist + weight transpose + x convert + bounds --------
// One dispatch, flat grid, role by block range:
//   [0,2560)         transpose 10 x (16x16) tiles of 32x32
//   [2560,12560)     convert x -> bf16 right half of m0  (10000 blocks!)
//   [12560,12600)    graph_bounds (sorted batch)
//   [12600,13225)    hist of dst into deg
__global__ __launch_bounds__(256) void prep_all(
    WPtrs wp, unsigned short* __restrict__ WT,
    const float* __restrict__ x_in, unsigned short* __restrict__ m0,
    const int* __restrict__ batch, int* __restrict__ gstart,
    const int* __restrict__ dstv, int* __restrict__ deg) {
  int bid = blockIdx.x;
  int tid = threadIdx.x;
  if (bid < 2560) {
    __shared__ float tile[32][33];
    int z = bid >> 8;                 // 0..9: layer z>>1, (z&1)=Ws
    int rem = bid & 255;
    int by = (rem >> 4) * 32, bx = (rem & 15) * 32;
    const float* W = wp.p[z];
    unsigned short* dst = WT + (size_t)(z >> 1) * DD * 1024 + (size_t)(z & 1) * DD;
    int tx = tid & 31, ty = tid >> 5;
    for (int i = ty; i < 32; i += 8)
      tile[i][tx] = W[(size_t)(by + i) * DD + bx + tx];
    __syncthreads();
    int addI = z & 1;
    for (int i = ty; i < 32; i += 8) {
      float v = tile[tx][i];
      if (addI && (by + tx) == (bx + i)) v += 1.0f;   // fold residual into Ws
      dst[(size_t)(bx + i) * 1024 + by + tx] = f2bf(v);
    }
  } else if (bid < 12560) {
    int i = (bid - 2560) * 256 + tid;                 // pair index
    if (i < NN * DD / 2) {
      float2 v = ((const float2*)x_in)[i];
      unsigned u = (unsigned)f2bf(v.x) | ((unsigned)f2bf(v.y) << 16);
      int e = i << 1;
      int row = e >> 9, col = e & 511;
      ((unsigned*)m0)[row * 512 + 256 + (col >> 1)] = u;
    }
  } else if (bid < 12600) {
    int i = (bid - 12560) * 256 + tid;
    if (i < NN) {
      int cur = batch[i];
      int prev = (i == 0) ? -1 : batch[i - 1];
      for (int g = prev + 1; g <= cur; ++g) gstart[g] = i;
      if (i == NN - 1)
        for (int g = cur + 1; g <= GG; ++g) gstart[g] = NN;
    }
  } else {
    int e = (bid - 12600) * 256 + tid;
    if (e < EE) atomicAdd(&deg[dstv[e]], 1);
  }
}

// ---------------- CSR scan + fill ----------------
__global__ void scan_offsets(const int* __restrict__ cnt, int* __restrict__ offs) {
  __shared__ int wpre[17];
  __shared__ int carry;
  int t = threadIdx.x;            // 1024 threads = 16 waves
  int lane = t & 63, wv = t >> 6;
  if (t == 0) carry = 0;
  __syncthreads();
  for (int base = 0; base < NN; base += 1024) {
    int i = base + t;
    int v = (i < NN) ? cnt[i] : 0;
    int s = v;
#pragma unroll
    for (int d = 1; d < 64; d <<= 1) {
      int o = __shfl_up(s, d, 64);
      if (lane >= d) s += o;
    }
    if (lane == 63) wpre[wv] = s;
    __syncthreads();
    if (t == 0) {
      int r = 0;
      for (int w = 0; w < 16; ++w) { int x = wpre[w]; wpre[w] = r; r += x; }
      wpre[16] = r;
    }
    __syncthreads();
    int incl = s + wpre[wv] + carry;
    if (i < NN) offs[i] = incl - v;   // exclusive prefix
    __syncthreads();
    if (t == 0) carry += wpre[16];
    __syncthreads();
  }
  if (t == 0) offs[NN] = carry;       // == EE
}

__global__ void fill_edges(const int* __restrict__ src, const int* __restrict__ dst,
                           const int* __restrict__ offs, int* __restrict__ fptr,
                           int* __restrict__ ssrc) {
  int e = blockIdx.x * 256 + threadIdx.x;
  if (e < EE) {
    int d = dst[e];
    int p = atomicAdd(&fptr[d], 1);
    ssrc[offs[d] + p] = src[e];
  }
}

// ---------------- segment sum: col-sliced + 2-node interleave ----------
// merged row = [agg(512) | x(512)] bf16 = 512 uints; x half = uints 256..511.
// Grid 5000: slice = bid&3 (XCD-sharded via bid%8 -> {s, s+4}), p = bid>>2,
// wave w handles node pair (p*4+w, p*4+w+5000) on that slice.
// 8+8 interleaved loads = 16 outstanding -> 2x MLP vs r7.
__global__ __launch_bounds__(256) void seg_sum2(unsigned short* __restrict__ merged,
                                                const int* __restrict__ offs,
                                                const int* __restrict__ ssrc) {
  int bid = blockIdx.x;
  int slice = bid & 3;
  int p = bid >> 2;                         // 0..1249
  int wave = threadIdx.x >> 6, lane = threadIdx.x & 63;
  int na = p * 4 + wave;                    // 0..4999
  int nb = na + 5000;                       // 5000..9999
  const unsigned* xw = (const unsigned*)merged;
  size_t co = 256 + slice * 64 + lane;      // uint offset within row
  int e0 = offs[na], f0 = offs[na + 1];
  int e1 = offs[nb], f1 = offs[nb + 1];
  float a0 = 0.f, a1 = 0.f, b0 = 0.f, b1 = 0.f;
#define LD(n, ee, i) unsigned n = xw[(size_t)ssrc[(ee) + (i)] * 512 + co]
#define AC(n, x0, x1)                                   \
  x0 += __builtin_bit_cast(float, n << 16);             \
  x1 += __builtin_bit_cast(float, n & 0xffff0000u)
  while (e0 + 8 <= f0 && e1 + 8 <= f1) {
    LD(u0, e0, 0); LD(u1, e0, 1); LD(u2, e0, 2); LD(u3, e0, 3);
    LD(u4, e0, 4); LD(u5, e0, 5); LD(u6, e0, 6); LD(u7, e0, 7);
    LD(w0, e1, 0); LD(w1, e1, 1); LD(w2, e1, 2); LD(w3, e1, 3);
    LD(w4, e1, 4); LD(w5, e1, 5); LD(w6, e1, 6); LD(w7, e1, 7);
    AC(u0, a0, a1); AC(u1, a0, a1); AC(u2, a0, a1); AC(u3, a0, a1);
    AC(u4, a0, a1); AC(u5, a0, a1); AC(u6, a0, a1); AC(u7, a0, a1);
    AC(w0, b0, b1); AC(w1, b0, b1); AC(w2, b0, b1); AC(w3, b0, b1);
    AC(w4, b0, b1); AC(w5, b0, b1); AC(w6, b0, b1); AC(w7, b0, b1);
    e0 += 8; e1 += 8;
  }
  for (; e0 + 4 <= f0; e0 += 4) {
    LD(u0, e0, 0); LD(u1, e0, 1); LD(u2, e0, 2); LD(u3, e0, 3);
    AC(u0, a0, a1); AC(u1, a0, a1); AC(u2, a0, a1); AC(u3, a0, a1);
  }
  for (; e0 < f0; ++e0) {
    LD(u0, e0, 0); AC(u0, a0, a1);
  }
  for (; e1 + 4 <= f1; e1 += 4) {
    LD(w0, e1, 0); LD(w1, e1, 1); LD(w2, e1, 2); LD(w3, e1, 3);
    AC(w0, b0, b1); AC(w1, b0, b1); AC(w2, b0, b1); AC(w3, b0, b1);
  }
  for (; e1 < f1; ++e1) {
    LD(w0, e1, 0); AC(w0, b0, b1);
  }
#undef LD
#undef AC
  unsigned oa = (unsigned)f2bf(a0) | ((unsigned)f2bf(a1) << 16);
  unsigned ob = (unsigned)f2bf(b0) | ((unsigned)f2bf(b1) << 16);
  ((unsigned*)merged)[(size_t)na * 512 + slice * 64 + lane] = oa;
  ((unsigned*)merged)[(size_t)nb * 512 + slice * 64 + lane] = ob;
}

// ---------------- fused layer GEMM (64x64 tile) --------------------------
// C[row,col] = sum_k merged[row][k] * WT[col][k]  (k 0..1023 = agg@Wr + x@(Ws+I))
// then + bias, ReLU, write bf16 into NEXT merged buffer's right half.
// Tile 64x64, BK=64, 4 waves as 2x2 (each 32x32), dbuf LDS (32 KB total) via
// global_load_lds(16B) with both-sides XOR chunk swizzle (conflict-free, r3).
// Grid 1256 = 8*157: clean bijective XCD swizzle; ~4.9 blocks/CU for TLP.
__global__ __launch_bounds__(256) void gemm_layer(
    const unsigned short* __restrict__ Am,    // merged cur [NN][1024]
    const unsigned short* __restrict__ Bw,    // [512 n][1024 k]
    const float* __restrict__ bias,
    unsigned short* __restrict__ xout,        // merged next (write right half)
    int do_relu) {
  __shared__ unsigned short Al[2][64 * 64];
  __shared__ unsigned short Bl[2][64 * 64];
  int tid = threadIdx.x;
  int lane = tid & 63, wave = tid >> 6;
  int wr = wave >> 1, wc = wave & 1;          // wave tile 32x32

  int orig = blockIdx.x;
  int wgid = (orig & 7) * 157 + (orig >> 3);  // bijective: 1256 = 8*157
  int brow = (wgid >> 3) * 64;                // 157 row panels (cover 10048)
  int bcol = (wgid & 7) * 64;                 // 8 col panels
  int lrow = lane & 15, lq = lane >> 4;

  f32x4 acc[2][2];
#pragma unroll
  for (int m = 0; m < 2; ++m)
#pragma unroll
    for (int n = 0; n < 2; ++n) acc[m][n] = (f32x4){0.f, 0.f, 0.f, 0.f};

  auto STAGE = [&](int buf, int t) {
    int k0 = t * 64;
#pragma unroll
    for (int i = 0; i < 2; ++i) {             // A: 64 rows x 8 chunks
      int idx = i * 256 + tid;
      int row = idx >> 3, c = idx & 7;
      int csw = (c ^ (row & 7)) * 8;
      int gr = brow + row;
      if (gr >= NN) gr = NN - 1;              // clamp; OOB rows never stored
      gload_lds16(Am + (size_t)gr * 1024 + k0 + csw, &Al[buf][idx * 8]);
    }
#pragma unroll
    for (int i = 0; i < 2; ++i) {             // B: 64 rows x 8 chunks
      int idx = i * 256 + tid;
      int row = idx >> 3, c = idx & 7;
      int csw = (c ^ (row & 7)) * 8;
      gload_lds16(Bw + (size_t)(bcol + row) * 1024 + k0 + csw, &Bl[buf][idx * 8]);
    }
  };

  STAGE(0, 0);
  __syncthreads();                            // buf0 ready
  int cur = 0;
#pragma unroll 1
  for (int t = 0; t < 16; ++t) {
    if (t < 15) STAGE(cur ^ 1, t + 1);        // in flight under compute
#pragma unroll
    for (int kk = 0; kk < 2; ++kk) {
      bf16x8 a[2], b[2];
      int lc = kk * 4 + lq;                   // logical 16B chunk 0..7
#pragma unroll
      for (int m = 0; m < 2; ++m) {
        int row = wr * 32 + m * 16 + lrow;
        a[m] = *(const bf16x8*)&Al[cur][row * 64 + ((lc ^ (lrow & 7)) * 8)];
      }
#pragma unroll
      for (int n = 0; n < 2; ++n) {
        int row = wc * 32 + n * 16 + lrow;
        b[n] = *(const bf16x8*)&Bl[cur][row * 64 + ((lc ^ (lrow & 7)) * 8)];
      }
#pragma unroll
      for (int m = 0; m < 2; ++m)
#pragma unroll
        for (int n = 0; n < 2; ++n)
          acc[m][n] = __builtin_amdgcn_mfma_f32_16x16x32_bf16(a[m], b[n], acc[m][n], 0, 0, 0);
    }
    __syncthreads();                          // compute done; next buf staged
    cur ^= 1;
  }

  // epilogue: C row=(lane>>4)*4+i, col=lane&15 within each 16x16 fragment
  int crow = lq * 4, ccol = lrow;
#pragma unroll
  for (int m = 0; m < 2; ++m) {
#pragma unroll
    for (int n = 0; n < 2; ++n) {
      int col = bcol + wc * 32 + n * 16 + ccol;
      float bv = bias[col];
#pragma unroll
      for (int i = 0; i < 4; ++i) {
        int row = brow + wr * 32 + m * 16 + crow + i;
        if (row < NN) {
          float v = acc[m][n][i] + bv;
          if (do_relu) v = fmaxf(v, 0.f);
          xout[(size_t)row * 1024 + 512 + col] = f2bf(v);
        }
      }
    }
  }
}

// ---------------- pooling ----------------
__global__ __launch_bounds__(256) void pool_partial(const unsigned short* __restrict__ mfin,
                                                    const int* __restrict__ gstart,
                                                    float* __restrict__ pooled) {
  int g = blockIdx.x, part = blockIdx.y;    // 8 parts per graph
  int t = threadIdx.x;                      // 256 threads: col pair 2t,2t+1
  int beg = gstart[g], end = gstart[g + 1];
  int n = end - beg;
  int per = (n + 7) >> 3;
  int b = beg + part * per;
  int e = b + per; if (e > end) e = end;
  if (b >= e) return;
  const unsigned* mw = (const unsigned*)mfin;
  float a0 = 0.f, a1 = 0.f;
  for (int r = b; r < e; ++r) {
    unsigned v = mw[(size_t)r * 512 + 256 + t];
    a0 += __builtin_bit_cast(float, v << 16);
    a1 += __builtin_bit_cast(float, v & 0xffff0000u);
  }
  atomicAdd(&pooled[g * DD + 2 * t], a0);
  atomicAdd(&pooled[g * DD + 2 * t + 1], a1);
}

// grid (GG, 4): each block computes 128-k-slice partial of out[g][*]
__global__ __launch_bounds__(128) void final_linear(const float* __restrict__ pooled,
                                                    const int* __restrict__ gstart,
                                                    const float* __restrict__ Wlin,
                                                    const float* __restrict__ blin,
                                                    float* __restrict__ out) {
  __shared__ float p[128];
  int g = blockIdx.x, kq = blockIdx.y;
  int o = threadIdx.x;
  int cnt = gstart[g + 1] - gstart[g];
  float inv = 1.0f / fmaxf((float)cnt, 1.0f);
  p[o] = pooled[g * DD + kq * 128 + o] * inv;
  __syncthreads();
  float s = (kq == 0) ? blin[o] : 0.f;
#pragma unroll 8
  for (int k = 0; k < 128; ++k)
    s += p[k] * Wlin[(size_t)(kq * 128 + k) * OUTC + o];
  atomicAdd(&out[g * OUTC + o], s);
}

// ---------------- host ----------------
extern "C" void kernel_launch(void* const* d_in, const int* in_sizes, int n_in,
                              void* d_out, int out_size, void* d_ws, size_t ws_size,
                              hipStream_t stream) {
  const float* x_in = (const float*)d_in[0];
  const int* ei = (const int*)d_in[1];
  const int* src = ei;
  const int* dst = ei + EE;
  const int* batch = (const int*)d_in[2];
  WPtrs wp;
  const float* bias[5];
  for (int l = 0; l < 5; ++l) {
    wp.p[2 * l] = (const float*)d_in[3 + 3 * l];      // Wr
    wp.p[2 * l + 1] = (const float*)d_in[4 + 3 * l];  // Ws
    bias[l] = (const float*)d_in[5 + 3 * l];
  }
  const float* Wlin = (const float*)d_in[18];
  const float* blin = (const float*)d_in[19];
  float* out = (float*)d_out;

  char* ws = (char*)d_ws;
  size_t off = 0;
  auto alloc = [&](size_t bytes) { size_t o = off; off += (bytes + 511) & ~(size_t)511; return o; };
  unsigned short* m0 = (unsigned short*)(ws + alloc((size_t)NN * 1024 * 2));
  unsigned short* m1 = (unsigned short*)(ws + alloc((size_t)NN * 1024 * 2));
  unsigned short* wt = (unsigned short*)(ws + alloc((size_t)5 * DD * 1024 * 2));
  int* deg = (int*)(ws + alloc((size_t)2 * NN * 4));   // deg | fptr contiguous
  int* fptr = deg + NN;
  int* offs = (int*)(ws + alloc((size_t)(NN + 1) * 4));
  int* ssrc = (int*)(ws + alloc((size_t)EE * 4));
  int* gstart = (int*)(ws + alloc((size_t)(GG + 1) * 4));
  float* pooled = (float*)(ws + alloc((size_t)GG * DD * 4));

  hipMemsetAsync(deg, 0, (size_t)2 * NN * 4, stream);  // deg + fptr
  hipMemsetAsync(pooled, 0, (size_t)GG * DD * 4, stream);
  hipMemsetAsync(out, 0, (size_t)GG * OUTC * 4, stream);

  // prep: hist + transpose(+I fold) + convert + graph bounds, one dispatch
  prep_all<<<13225, 256, 0, stream>>>(wp, wt, x_in, m0, batch, gstart, dst, deg);

  // CSR scan + fill
  scan_offsets<<<1, 1024, 0, stream>>>(deg, offs);
  fill_edges<<<(EE + 255) / 256, 256, 0, stream>>>(src, dst, offs, fptr, ssrc);

  // layers
  unsigned short* mc = m0;
  unsigned short* mn = m1;
  for (int l = 0; l < 5; ++l) {
    seg_sum2<<<5000, 256, 0, stream>>>(mc, offs, ssrc);
    gemm_layer<<<NBLK2, 256, 0, stream>>>(mc, wt + (size_t)l * DD * 1024,
                                          bias[l], mn, l < 4 ? 1 : 0);
    unsigned short* t = mc; mc = mn; mn = t;
  }

  // pooling + final linear (mc == final merged buffer after 5 swaps)
  dim3 pgrid(GG, 8);
  pool_partial<<<pgrid, 256, 0, stream>>>(mc, gstart, pooled);
  dim3 fgrid(GG, 4);
  final_linear<<<fgrid, 128, 0, stream>>>(pooled, gstart, Wlin, blin, out);
}

// Round 10
// 258.866 us; speedup vs baseline: 1.1172x; 1.1172x over previous
//
#include <hip/hip_runtime.h>
#include <hip/hip_bf16.h>

#define NN 10000
#define EE 160000
#define DD 512
#define GG 64
#define OUTC 128
#define NBLK 628            // gemm grid: 157 row-panels x 4 col-panels

typedef __attribute__((ext_vector_type(8))) short bf16x8;
typedef __attribute__((ext_vector_type(4))) float f32x4;

static __device__ __forceinline__ unsigned short f2bf(float f) {
  unsigned u = __builtin_bit_cast(unsigned, f);
  unsigned rounding = 0x7fffu + ((u >> 16) & 1u);
  u += rounding;
  return (unsigned short)(u >> 16);
}

static __device__ __forceinline__ void gload_lds16(const void* g, void* l) {
  __builtin_amdgcn_global_load_lds(
      (const __attribute__((address_space(1))) unsigned*)g,
      (__attribute__((address_space(3))) unsigned*)l, 16, 0, 0);
}

struct WPtrs { const float* p[10]; };

// ---------------- prep: hist + weight transpose + x convert + bounds --------
// One dispatch, flat grid, role by block range:
//   [0,2560)         transpose 10 x (16x16) tiles of 32x32
//   [2560,12560)     convert x -> bf16 right half of m0  (10000 blocks)
//   [12560,12600)    graph_bounds (sorted batch)
//   [12600,13225)    hist of dst into deg
__global__ __launch_bounds__(256) void prep_all(
    WPtrs wp, unsigned short* __restrict__ WT,
    const float* __restrict__ x_in, unsigned short* __restrict__ m0,
    const int* __restrict__ batch, int* __restrict__ gstart,
    const int* __restrict__ dstv, int* __restrict__ deg) {
  int bid = blockIdx.x;
  int tid = threadIdx.x;
  if (bid < 2560) {
    __shared__ float tile[32][33];
    int z = bid >> 8;                 // 0..9: layer z>>1, (z&1)=Ws
    int rem = bid & 255;
    int by = (rem >> 4) * 32, bx = (rem & 15) * 32;
    const float* W = wp.p[z];
    unsigned short* dst = WT + (size_t)(z >> 1) * DD * 1024 + (size_t)(z & 1) * DD;
    int tx = tid & 31, ty = tid >> 5;
    for (int i = ty; i < 32; i += 8)
      tile[i][tx] = W[(size_t)(by + i) * DD + bx + tx];
    __syncthreads();
    int addI = z & 1;
    for (int i = ty; i < 32; i += 8) {
      float v = tile[tx][i];
      if (addI && (by + tx) == (bx + i)) v += 1.0f;   // fold residual into Ws
      dst[(size_t)(bx + i) * 1024 + by + tx] = f2bf(v);
    }
  } else if (bid < 12560) {
    int i = (bid - 2560) * 256 + tid;                 // pair index
    if (i < NN * DD / 2) {
      float2 v = ((const float2*)x_in)[i];
      unsigned u = (unsigned)f2bf(v.x) | ((unsigned)f2bf(v.y) << 16);
      int e = i << 1;
      int row = e >> 9, col = e & 511;
      ((unsigned*)m0)[row * 512 + 256 + (col >> 1)] = u;
    }
  } else if (bid < 12600) {
    int i = (bid - 12560) * 256 + tid;
    if (i < NN) {
      int cur = batch[i];
      int prev = (i == 0) ? -1 : batch[i - 1];
      for (int g = prev + 1; g <= cur; ++g) gstart[g] = i;
      if (i == NN - 1)
        for (int g = cur + 1; g <= GG; ++g) gstart[g] = NN;
    }
  } else {
    int e = (bid - 12600) * 256 + tid;
    if (e < EE) atomicAdd(&deg[dstv[e]], 1);
  }
}

// ---------------- CSR scan + fill ----------------
__global__ void scan_offsets(const int* __restrict__ cnt, int* __restrict__ offs) {
  __shared__ int wpre[17];
  __shared__ int carry;
  int t = threadIdx.x;            // 1024 threads = 16 waves
  int lane = t & 63, wv = t >> 6;
  if (t == 0) carry = 0;
  __syncthreads();
  for (int base = 0; base < NN; base += 1024) {
    int i = base + t;
    int v = (i < NN) ? cnt[i] : 0;
    int s = v;
#pragma unroll
    for (int d = 1; d < 64; d <<= 1) {
      int o = __shfl_up(s, d, 64);
      if (lane >= d) s += o;
    }
    if (lane == 63) wpre[wv] = s;
    __syncthreads();
    if (t == 0) {
      int r = 0;
      for (int w = 0; w < 16; ++w) { int x = wpre[w]; wpre[w] = r; r += x; }
      wpre[16] = r;
    }
    __syncthreads();
    int incl = s + wpre[wv] + carry;
    if (i < NN) offs[i] = incl - v;   // exclusive prefix
    __syncthreads();
    if (t == 0) carry += wpre[16];
    __syncthreads();
  }
  if (t == 0) offs[NN] = carry;       // == EE
}

__global__ void fill_edges(const int* __restrict__ src, const int* __restrict__ dst,
                           const int* __restrict__ offs, int* __restrict__ fptr,
                           int* __restrict__ ssrc) {
  int e = blockIdx.x * 256 + threadIdx.x;
  if (e < EE) {
    int d = dst[e];
    int p = atomicAdd(&fptr[d], 1);
    ssrc[offs[d] + p] = src[e];
  }
}

// ---------------- segment sum: col-sliced + 2-node interleave ----------
// merged row = [agg(512) | x(512)] bf16 = 512 uints; x half = uints 256..511.
// Grid 5000: slice = bid&3 (XCD-sharded via bid%8 -> {s, s+4}), p = bid>>2,
// wave w handles node pair (p*4+w, p*4+w+5000) on that slice.
// 8+8 interleaved loads = 16 outstanding.
__global__ __launch_bounds__(256) void seg_sum2(unsigned short* __restrict__ merged,
                                                const int* __restrict__ offs,
                                                const int* __restrict__ ssrc) {
  int bid = blockIdx.x;
  int slice = bid & 3;
  int p = bid >> 2;                         // 0..1249
  int wave = threadIdx.x >> 6, lane = threadIdx.x & 63;
  int na = p * 4 + wave;                    // 0..4999
  int nb = na + 5000;                       // 5000..9999
  const unsigned* xw = (const unsigned*)merged;
  size_t co = 256 + slice * 64 + lane;      // uint offset within row
  int e0 = offs[na], f0 = offs[na + 1];
  int e1 = offs[nb], f1 = offs[nb + 1];
  float a0 = 0.f, a1 = 0.f, b0 = 0.f, b1 = 0.f;
#define LD(n, ee, i) unsigned n = xw[(size_t)ssrc[(ee) + (i)] * 512 + co]
#define AC(n, x0, x1)                                   \
  x0 += __builtin_bit_cast(float, n << 16);             \
  x1 += __builtin_bit_cast(float, n & 0xffff0000u)
  while (e0 + 8 <= f0 && e1 + 8 <= f1) {
    LD(u0, e0, 0); LD(u1, e0, 1); LD(u2, e0, 2); LD(u3, e0, 3);
    LD(u4, e0, 4); LD(u5, e0, 5); LD(u6, e0, 6); LD(u7, e0, 7);
    LD(w0, e1, 0); LD(w1, e1, 1); LD(w2, e1, 2); LD(w3, e1, 3);
    LD(w4, e1, 4); LD(w5, e1, 5); LD(w6, e1, 6); LD(w7, e1, 7);
    AC(u0, a0, a1); AC(u1, a0, a1); AC(u2, a0, a1); AC(u3, a0, a1);
    AC(u4, a0, a1); AC(u5, a0, a1); AC(u6, a0, a1); AC(u7, a0, a1);
    AC(w0, b0, b1); AC(w1, b0, b1); AC(w2, b0, b1); AC(w3, b0, b1);
    AC(w4, b0, b1); AC(w5, b0, b1); AC(w6, b0, b1); AC(w7, b0, b1);
    e0 += 8; e1 += 8;
  }
  for (; e0 + 4 <= f0; e0 += 4) {
    LD(u0, e0, 0); LD(u1, e0, 1); LD(u2, e0, 2); LD(u3, e0, 3);
    AC(u0, a0, a1); AC(u1, a0, a1); AC(u2, a0, a1); AC(u3, a0, a1);
  }
  for (; e0 < f0; ++e0) {
    LD(u0, e0, 0); AC(u0, a0, a1);
  }
  for (; e1 + 4 <= f1; e1 += 4) {
    LD(w0, e1, 0); LD(w1, e1, 1); LD(w2, e1, 2); LD(w3, e1, 3);
    AC(w0, b0, b1); AC(w1, b0, b1); AC(w2, b0, b1); AC(w3, b0, b1);
  }
  for (; e1 < f1; ++e1) {
    LD(w0, e1, 0); AC(w0, b0, b1);
  }
#undef LD
#undef AC
  unsigned oa = (unsigned)f2bf(a0) | ((unsigned)f2bf(a1) << 16);
  unsigned ob = (unsigned)f2bf(b0) | ((unsigned)f2bf(b1) << 16);
  ((unsigned*)merged)[(size_t)na * 512 + slice * 64 + lane] = oa;
  ((unsigned*)merged)[(size_t)nb * 512 + slice * 64 + lane] = ob;
}

// ---------------- fused layer GEMM (64x128 tile, r7 config) --------------
// C[row,col] = sum_k merged[row][k] * WT[col][k]  (k 0..1023 = agg@Wr + x@(Ws+I))
// then + bias, ReLU, write bf16 into NEXT merged buffer's right half.
// Tile 64x128, BK=64, 4 waves (each 32x64), dbuf LDS (48 KB) via
// global_load_lds(16B) with both-sides XOR chunk swizzle (conflict-free, r3).
// Grid 628, bijective XCD swizzle (628 = 8*78+4, m204).
__global__ __launch_bounds__(256) void gemm_layer(
    const unsigned short* __restrict__ Am,    // merged cur [NN][1024]
    const unsigned short* __restrict__ Bw,    // [512 n][1024 k]
    const float* __restrict__ bias,
    unsigned short* __restrict__ xout,        // merged next (write right half)
    int do_relu) {
  __shared__ unsigned short Al[2][64 * 64];
  __shared__ unsigned short Bl[2][128 * 64];
  int tid = threadIdx.x;
  int lane = tid & 63, wave = tid >> 6;
  int wr = wave >> 1, wc = wave & 1;        // wave tile 32 rows x 64 cols

  // bijective XCD swizzle: nwg=628, q=78, r=4
  int orig = blockIdx.x;
  int xcd = orig & 7, cidx = orig >> 3;
  int wgid = (xcd < 4) ? xcd * 79 + cidx : 316 + (xcd - 4) * 78 + cidx;
  int brow = (wgid >> 2) * 64;
  int bcol = (wgid & 3) * 128;
  int lrow = lane & 15, lq = lane >> 4;

  f32x4 acc[2][4];
#pragma unroll
  for (int m = 0; m < 2; ++m)
#pragma unroll
    for (int n = 0; n < 4; ++n) acc[m][n] = (f32x4){0.f, 0.f, 0.f, 0.f};

  auto STAGE = [&](int buf, int t) {
    int k0 = t * 64;
#pragma unroll
    for (int i = 0; i < 2; ++i) {           // A: 64 rows x 8 chunks
      int idx = i * 256 + tid;
      int row = idx >> 3, c = idx & 7;
      int csw = (c ^ (row & 7)) * 8;
      int gr = brow + row;
      if (gr >= NN) gr = NN - 1;            // clamp; OOB rows never stored
      gload_lds16(Am + (size_t)gr * 1024 + k0 + csw, &Al[buf][idx * 8]);
    }
#pragma unroll
    for (int i = 0; i < 4; ++i) {           // B: 128 rows x 8 chunks
      int idx = i * 256 + tid;
      int row = idx >> 3, c = idx & 7;
      int csw = (c ^ (row & 7)) * 8;
      gload_lds16(Bw + (size_t)(bcol + row) * 1024 + k0 + csw, &Bl[buf][idx * 8]);
    }
  };

  STAGE(0, 0);
  __syncthreads();                            // buf0 ready
  int cur = 0;
#pragma unroll 1
  for (int t = 0; t < 16; ++t) {
    if (t < 15) STAGE(cur ^ 1, t + 1);        // in flight under compute
#pragma unroll
    for (int kk = 0; kk < 2; ++kk) {
      bf16x8 a[2], b[4];
      int lc = kk * 4 + lq;                   // logical 16B chunk 0..7
#pragma unroll
      for (int m = 0; m < 2; ++m) {
        int row = wr * 32 + m * 16 + lrow;
        a[m] = *(const bf16x8*)&Al[cur][row * 64 + ((lc ^ (lrow & 7)) * 8)];
      }
#pragma unroll
      for (int n = 0; n < 4; ++n) {
        int row = wc * 64 + n * 16 + lrow;
        b[n] = *(const bf16x8*)&Bl[cur][row * 64 + ((lc ^ (lrow & 7)) * 8)];
      }
#pragma unroll
      for (int m = 0; m < 2; ++m)
#pragma unroll
        for (int n = 0; n < 4; ++n)
          acc[m][n] = __builtin_amdgcn_mfma_f32_16x16x32_bf16(a[m], b[n], acc[m][n], 0, 0, 0);
    }
    __syncthreads();                          // compute done; next buf staged
    cur ^= 1;
  }

  // epilogue: C row=(lane>>4)*4+i, col=lane&15 within each 16x16 fragment
  int crow = lq * 4, ccol = lrow;
#pragma unroll
  for (int m = 0; m < 2; ++m) {
#pragma unroll
    for (int n = 0; n < 4; ++n) {
      int col = bcol + wc * 64 + n * 16 + ccol;
      float bv = bias[col];
#pragma unroll
      for (int i = 0; i < 4; ++i) {
        int row = brow + wr * 32 + m * 16 + crow + i;
        if (row < NN) {
          float v = acc[m][n][i] + bv;
          if (do_relu) v = fmaxf(v, 0.f);
          xout[(size_t)row * 1024 + 512 + col] = f2bf(v);
        }
      }
    }
  }
}

// ---------------- pooling ----------------
__global__ __launch_bounds__(256) void pool_partial(const unsigned short* __restrict__ mfin,
                                                    const int* __restrict__ gstart,
                                                    float* __restrict__ pooled) {
  int g = blockIdx.x, part = blockIdx.y;    // 8 parts per graph
  int t = threadIdx.x;                      // 256 threads: col pair 2t,2t+1
  int beg = gstart[g], end = gstart[g + 1];
  int n = end - beg;
  int per = (n + 7) >> 3;
  int b = beg + part * per;
  int e = b + per; if (e > end) e = end;
  if (b >= e) return;
  const unsigned* mw = (const unsigned*)mfin;
  float a0 = 0.f, a1 = 0.f;
  for (int r = b; r < e; ++r) {
    unsigned v = mw[(size_t)r * 512 + 256 + t];
    a0 += __builtin_bit_cast(float, v << 16);
    a1 += __builtin_bit_cast(float, v & 0xffff0000u);
  }
  atomicAdd(&pooled[g * DD + 2 * t], a0);
  atomicAdd(&pooled[g * DD + 2 * t + 1], a1);
}

// grid (GG, 4): each block computes 128-k-slice partial of out[g][*]
__global__ __launch_bounds__(128) void final_linear(const float* __restrict__ pooled,
                                                    const int* __restrict__ gstart,
                                                    const float* __restrict__ Wlin,
                                                    const float* __restrict__ blin,
                                                    float* __restrict__ out) {
  __shared__ float p[128];
  int g = blockIdx.x, kq = blockIdx.y;
  int o = threadIdx.x;
  int cnt = gstart[g + 1] - gstart[g];
  float inv = 1.0f / fmaxf((float)cnt, 1.0f);
  p[o] = pooled[g * DD + kq * 128 + o] * inv;
  __syncthreads();
  float s = (kq == 0) ? blin[o] : 0.f;
#pragma unroll 8
  for (int k = 0; k < 128; ++k)
    s += p[k] * Wlin[(size_t)(kq * 128 + k) * OUTC + o];
  atomicAdd(&out[g * OUTC + o], s);
}

// ---------------- host ----------------
extern "C" void kernel_launch(void* const* d_in, const int* in_sizes, int n_in,
                              void* d_out, int out_size, void* d_ws, size_t ws_size,
                              hipStream_t stream) {
  const float* x_in = (const float*)d_in[0];
  const int* ei = (const int*)d_in[1];
  const int* src = ei;
  const int* dst = ei + EE;
  const int* batch = (const int*)d_in[2];
  WPtrs wp;
  const float* bias[5];
  for (int l = 0; l < 5; ++l) {
    wp.p[2 * l] = (const float*)d_in[3 + 3 * l];      // Wr
    wp.p[2 * l + 1] = (const float*)d_in[4 + 3 * l];  // Ws
    bias[l] = (const float*)d_in[5 + 3 * l];
  }
  const float* Wlin = (const float*)d_in[18];
  const float* blin = (const float*)d_in[19];
  float* out = (float*)d_out;

  char* ws = (char*)d_ws;
  size_t off = 0;
  auto alloc = [&](size_t bytes) { size_t o = off; off += (bytes + 511) & ~(size_t)511; return o; };
  unsigned short* m0 = (unsigned short*)(ws + alloc((size_t)NN * 1024 * 2));
  unsigned short* m1 = (unsigned short*)(ws + alloc((size_t)NN * 1024 * 2));
  unsigned short* wt = (unsigned short*)(ws + alloc((size_t)5 * DD * 1024 * 2));
  int* deg = (int*)(ws + alloc((size_t)2 * NN * 4));   // deg | fptr contiguous
  int* fptr = deg + NN;
  int* offs = (int*)(ws + alloc((size_t)(NN + 1) * 4));
  int* ssrc = (int*)(ws + alloc((size_t)EE * 4));
  int* gstart = (int*)(ws + alloc((size_t)(GG + 1) * 4));
  float* pooled = (float*)(ws + alloc((size_t)GG * DD * 4));

  hipMemsetAsync(deg, 0, (size_t)2 * NN * 4, stream);  // deg + fptr
  hipMemsetAsync(pooled, 0, (size_t)GG * DD * 4, stream);
  hipMemsetAsync(out, 0, (size_t)GG * OUTC * 4, stream);

  // prep: hist + transpose(+I fold) + convert + graph bounds, one dispatch
  prep_all<<<13225, 256, 0, stream>>>(wp, wt, x_in, m0, batch, gstart, dst, deg);

  // CSR scan + fill
  scan_offsets<<<1, 1024, 0, stream>>>(deg, offs);
  fill_edges<<<(EE + 255) / 256, 256, 0, stream>>>(src, dst, offs, fptr, ssrc);

  // layers
  unsigned short* mc = m0;
  unsigned short* mn = m1;
  for (int l = 0; l < 5; ++l) {
    seg_sum2<<<5000, 256, 0, stream>>>(mc, offs, ssrc);
    gemm_layer<<<NBLK, 256, 0, stream>>>(mc, wt + (size_t)l * DD * 1024,
                                         bias[l], mn, l < 4 ? 1 : 0);
    unsigned short* t = mc; mc = mn; mn = t;
  }

  // pooling + final linear (mc == final merged buffer after 5 swaps)
  dim3 pgrid(GG, 8);
  pool_partial<<<pgrid, 256, 0, stream>>>(mc, gstart, pooled);
  dim3 fgrid(GG, 4);
  final_linear<<<fgrid, 128, 0, stream>>>(pooled, gstart, Wlin, blin, out);
}